// Round 1
// baseline (224.448 us; speedup 1.0000x reference)
//
#include <hip/hip_runtime.h>

#define LN_EPS 1e-5f

typedef float v4f __attribute__((ext_vector_type(4)));

constexpr int BLOCK = 256;
constexpr int RPT   = 4;             // rows per thread
constexpr int RPB   = BLOCK * RPT;   // 1024 rows per block

__global__ __launch_bounds__(BLOCK) void ln_linear_softmax_kernel(
    const v4f*   __restrict__ x,     // [n] rows of 4 floats
    const float* __restrict__ W,     // [4,3] row-major
    const float* __restrict__ gamma, // [4]
    const float* __restrict__ beta,  // [4]
    v4f*         __restrict__ out4,  // out viewed as float4 (n*3/4 elements)
    int n)
{
    __shared__ float lds[RPB * 3];    // 12 KB

    const int  tid  = threadIdx.x;
    const long base = (long)blockIdx.x * RPB;

    const v4f g = *(const v4f*)gamma;
    const v4f b = *(const v4f*)beta;
    const v4f* W4 = (const v4f*)W;
    const v4f w0 = W4[0]; // W00 W01 W02 W10
    const v4f w1 = W4[1]; // W11 W12 W20 W21
    const v4f w2 = W4[2]; // W22 W30 W31 W32

    #pragma unroll
    for (int k = 0; k < RPT; ++k) {
        const int  rl  = tid + k * BLOCK;
        const long row = base + rl;
        if (row < n) {
            // Regular (cached) load: re-poison leaves x resident in L2/L3;
            // an nt-flagged load marks lines evict-first and forfeits that.
            v4f v = x[row];

            // LayerNorm over 4
            float mu = (v.x + v.y + v.z + v.w) * 0.25f;
            float dx = v.x - mu, dy = v.y - mu, dz = v.z - mu, dw = v.w - mu;
            float var = (dx*dx + dy*dy + dz*dz + dw*dw) * 0.25f;
            float rs  = rsqrtf(var + LN_EPS);

            float h0 = dx * rs * g.x + b.x;
            float h1 = dy * rs * g.y + b.y;
            float h2 = dz * rs * g.z + b.z;
            float h3 = dw * rs * g.w + b.w;

            // h @ W  (4 -> 3)
            float l0 = h0*w0.x + h1*w0.w + h2*w1.z + h3*w2.y;
            float l1 = h0*w0.y + h1*w1.x + h2*w1.w + h3*w2.z;
            float l2 = h0*w0.z + h1*w1.y + h2*w2.x + h3*w2.w;

            // softmax over 3
            float m   = fmaxf(l0, fmaxf(l1, l2));
            float e0  = __expf(l0 - m);
            float e1  = __expf(l1 - m);
            float e2  = __expf(l2 - m);
            float inv = 1.0f / (e0 + e1 + e2);

            // LDS: dword stride 3 -> 2 lanes/bank (free)
            lds[rl*3 + 0] = e0 * inv;
            lds[rl*3 + 1] = e1 * inv;
            lds[rl*3 + 2] = e2 * inv;
        }
    }

    __syncthreads();

    // Cooperative packed store: 768 float4s per block, fully coalesced.
    const v4f* lds4  = (const v4f*)lds;
    const long obase = (long)blockIdx.x * (RPB * 3 / 4);
    const long on4   = ((long)n * 3) / 4;
    #pragma unroll
    for (int k = 0; k < 3; ++k) {
        const long oi = obase + tid + k * BLOCK;
        if (oi < on4) {
            __builtin_nontemporal_store(lds4[tid + k * BLOCK], &out4[oi]);
        }
    }
}

extern "C" void kernel_launch(void* const* d_in, const int* in_sizes, int n_in,
                              void* d_out, int out_size, void* d_ws, size_t ws_size,
                              hipStream_t stream) {
    const float* x     = (const float*)d_in[0];
    const float* W     = (const float*)d_in[1];
    const float* gamma = (const float*)d_in[2];
    const float* beta  = (const float*)d_in[3];
    v4f* out4 = (v4f*)d_out;

    int n = in_sizes[0] / 4;                 // number of rows (8,388,608)
    int grid = (n + RPB - 1) / RPB;          // 8192 blocks
    ln_linear_softmax_kernel<<<grid, BLOCK, 0, stream>>>(
        (const v4f*)x, W, gamma, beta, out4, n);
}

// Round 2
// 213.410 us; speedup vs baseline: 1.0517x; 1.0517x over previous
//
#include <hip/hip_runtime.h>

#define LN_EPS 1e-5f

typedef float v4f __attribute__((ext_vector_type(4)));

constexpr int BLOCK = 256;
constexpr int RPT   = 4;             // rows per thread
constexpr int RPB   = BLOCK * RPT;   // 1024 rows per block

__global__ __launch_bounds__(BLOCK) void ln_linear_softmax_kernel(
    const v4f*   __restrict__ x,     // [n] rows of 4 floats
    const float* __restrict__ W,     // [4,3] row-major
    const float* __restrict__ gamma, // [4]
    const float* __restrict__ beta,  // [4]
    v4f*         __restrict__ out4,  // out viewed as float4 (n*3/4 elements)
    int n)
{
    __shared__ float lds[RPB * 3];    // 12 KB

    const int  tid  = threadIdx.x;
    const long base = (long)blockIdx.x * RPB;

    const v4f g = *(const v4f*)gamma;
    const v4f b = *(const v4f*)beta;
    const v4f* W4 = (const v4f*)W;
    const v4f w0 = W4[0]; // W00 W01 W02 W10
    const v4f w1 = W4[1]; // W11 W12 W20 W21
    const v4f w2 = W4[2]; // W22 W30 W31 W32

    v4f v[RPT];

    if (base + RPB <= (long)n) {
        // Full block (always taken for n = 8M): unguarded back-to-back
        // NT loads — no per-row exec-mask dance, maximal loads-in-flight.
        #pragma unroll
        for (int k = 0; k < RPT; ++k)
            v[k] = __builtin_nontemporal_load(&x[base + tid + k * BLOCK]);

        #pragma unroll
        for (int k = 0; k < RPT; ++k) {
            const int rl = tid + k * BLOCK;
            v4f q = v[k];

            float mu = (q.x + q.y + q.z + q.w) * 0.25f;
            float dx = q.x - mu, dy = q.y - mu, dz = q.z - mu, dw = q.w - mu;
            float var = (dx*dx + dy*dy + dz*dz + dw*dw) * 0.25f;
            float rs  = rsqrtf(var + LN_EPS);

            float h0 = dx * rs * g.x + b.x;
            float h1 = dy * rs * g.y + b.y;
            float h2 = dz * rs * g.z + b.z;
            float h3 = dw * rs * g.w + b.w;

            float l0 = h0*w0.x + h1*w0.w + h2*w1.z + h3*w2.y;
            float l1 = h0*w0.y + h1*w1.x + h2*w1.w + h3*w2.z;
            float l2 = h0*w0.z + h1*w1.y + h2*w2.x + h3*w2.w;

            float m   = fmaxf(l0, fmaxf(l1, l2));
            float e0  = __expf(l0 - m);
            float e1  = __expf(l1 - m);
            float e2  = __expf(l2 - m);
            float inv = 1.0f / (e0 + e1 + e2);

            lds[rl*3 + 0] = e0 * inv;
            lds[rl*3 + 1] = e1 * inv;
            lds[rl*3 + 2] = e2 * inv;
        }
    } else {
        // Tail block (never hit for the bench shape, kept for correctness).
        #pragma unroll
        for (int k = 0; k < RPT; ++k) {
            const int  rl  = tid + k * BLOCK;
            const long row = base + rl;
            if (row < n) {
                v4f q = __builtin_nontemporal_load(&x[row]);

                float mu = (q.x + q.y + q.z + q.w) * 0.25f;
                float dx = q.x - mu, dy = q.y - mu, dz = q.z - mu, dw = q.w - mu;
                float var = (dx*dx + dy*dy + dz*dz + dw*dw) * 0.25f;
                float rs  = rsqrtf(var + LN_EPS);

                float h0 = dx * rs * g.x + b.x;
                float h1 = dy * rs * g.y + b.y;
                float h2 = dz * rs * g.z + b.z;
                float h3 = dw * rs * g.w + b.w;

                float l0 = h0*w0.x + h1*w0.w + h2*w1.z + h3*w2.y;
                float l1 = h0*w0.y + h1*w1.x + h2*w1.w + h3*w2.z;
                float l2 = h0*w0.z + h1*w1.y + h2*w2.x + h3*w2.w;

                float m   = fmaxf(l0, fmaxf(l1, l2));
                float e0  = __expf(l0 - m);
                float e1  = __expf(l1 - m);
                float e2  = __expf(l2 - m);
                float inv = 1.0f / (e0 + e1 + e2);

                lds[rl*3 + 0] = e0 * inv;
                lds[rl*3 + 1] = e1 * inv;
                lds[rl*3 + 2] = e2 * inv;
            }
        }
    }

    __syncthreads();

    // Cooperative packed store: 768 float4s per block, fully coalesced.
    const v4f* lds4  = (const v4f*)lds;
    const long obase = (long)blockIdx.x * (RPB * 3 / 4);
    const long on4   = ((long)n * 3) / 4;
    #pragma unroll
    for (int k = 0; k < 3; ++k) {
        const long oi = obase + tid + k * BLOCK;
        if (oi < on4) {
            __builtin_nontemporal_store(lds4[tid + k * BLOCK], &out4[oi]);
        }
    }
}

extern "C" void kernel_launch(void* const* d_in, const int* in_sizes, int n_in,
                              void* d_out, int out_size, void* d_ws, size_t ws_size,
                              hipStream_t stream) {
    const float* x     = (const float*)d_in[0];
    const float* W     = (const float*)d_in[1];
    const float* gamma = (const float*)d_in[2];
    const float* beta  = (const float*)d_in[3];
    v4f* out4 = (v4f*)d_out;

    int n = in_sizes[0] / 4;                 // number of rows (8,388,608)
    int grid = (n + RPB - 1) / RPB;          // 8192 blocks
    ln_linear_softmax_kernel<<<grid, BLOCK, 0, stream>>>(
        (const v4f*)x, W, gamma, beta, out4, n);
}

// Round 3
// 211.444 us; speedup vs baseline: 1.0615x; 1.0093x over previous
//
#include <hip/hip_runtime.h>

#define LN_EPS 1e-5f

typedef float v4f __attribute__((ext_vector_type(4)));

constexpr int BLOCK = 512;
constexpr int RPT   = 4;             // rows per thread
constexpr int RPB   = BLOCK * RPT;   // 2048 rows per block

__global__ __launch_bounds__(BLOCK) void ln_linear_softmax_kernel(
    const v4f*   __restrict__ x,     // [n] rows of 4 floats
    const float* __restrict__ W,     // [4,3] row-major
    const float* __restrict__ gamma, // [4]
    const float* __restrict__ beta,  // [4]
    v4f*         __restrict__ out4,  // out viewed as float4 (n*3/4 elements)
    int n)
{
    __shared__ float lds[RPB * 3];    // 24 KB

    const int  tid  = threadIdx.x;
    const long base = (long)blockIdx.x * RPB;
    const bool full = (base + RPB <= (long)n);

    const v4f g = *(const v4f*)gamma;
    const v4f b = *(const v4f*)beta;
    const v4f* W4 = (const v4f*)W;
    const v4f w0 = W4[0]; // W00 W01 W02 W10
    const v4f w1 = W4[1]; // W11 W12 W20 W21
    const v4f w2 = W4[2]; // W22 W30 W31 W32

    v4f v[RPT];

    if (full) {
        // Hot path (always taken for n = 8M): unguarded back-to-back
        // NT loads — no per-row exec masking, maximal loads in flight.
        #pragma unroll
        for (int k = 0; k < RPT; ++k)
            v[k] = __builtin_nontemporal_load(&x[base + tid + k * BLOCK]);

        #pragma unroll
        for (int k = 0; k < RPT; ++k) {
            const int rl = tid + k * BLOCK;
            v4f q = v[k];

            float mu = (q.x + q.y + q.z + q.w) * 0.25f;
            float dx = q.x - mu, dy = q.y - mu, dz = q.z - mu, dw = q.w - mu;
            float var = (dx*dx + dy*dy + dz*dz + dw*dw) * 0.25f;
            float rs  = rsqrtf(var + LN_EPS);

            float h0 = dx * rs * g.x + b.x;
            float h1 = dy * rs * g.y + b.y;
            float h2 = dz * rs * g.z + b.z;
            float h3 = dw * rs * g.w + b.w;

            float l0 = h0*w0.x + h1*w0.w + h2*w1.z + h3*w2.y;
            float l1 = h0*w0.y + h1*w1.x + h2*w1.w + h3*w2.z;
            float l2 = h0*w0.z + h1*w1.y + h2*w2.x + h3*w2.w;

            float m   = fmaxf(l0, fmaxf(l1, l2));
            float e0  = __expf(l0 - m);
            float e1  = __expf(l1 - m);
            float e2  = __expf(l2 - m);
            float inv = 1.0f / (e0 + e1 + e2);

            lds[rl*3 + 0] = e0 * inv;
            lds[rl*3 + 1] = e1 * inv;
            lds[rl*3 + 2] = e2 * inv;
        }
    } else {
        // Tail block (never hit for the bench shape, kept for correctness).
        #pragma unroll
        for (int k = 0; k < RPT; ++k) {
            const int  rl  = tid + k * BLOCK;
            const long row = base + rl;
            if (row < n) {
                v4f q = __builtin_nontemporal_load(&x[row]);

                float mu = (q.x + q.y + q.z + q.w) * 0.25f;
                float dx = q.x - mu, dy = q.y - mu, dz = q.z - mu, dw = q.w - mu;
                float var = (dx*dx + dy*dy + dz*dz + dw*dw) * 0.25f;
                float rs  = rsqrtf(var + LN_EPS);

                float h0 = dx * rs * g.x + b.x;
                float h1 = dy * rs * g.y + b.y;
                float h2 = dz * rs * g.z + b.z;
                float h3 = dw * rs * g.w + b.w;

                float l0 = h0*w0.x + h1*w0.w + h2*w1.z + h3*w2.y;
                float l1 = h0*w0.y + h1*w1.x + h2*w1.w + h3*w2.z;
                float l2 = h0*w0.z + h1*w1.y + h2*w2.x + h3*w2.w;

                float m   = fmaxf(l0, fmaxf(l1, l2));
                float e0  = __expf(l0 - m);
                float e1  = __expf(l1 - m);
                float e2  = __expf(l2 - m);
                float inv = 1.0f / (e0 + e1 + e2);

                lds[rl*3 + 0] = e0 * inv;
                lds[rl*3 + 1] = e1 * inv;
                lds[rl*3 + 2] = e2 * inv;
            }
        }
    }

    __syncthreads();

    // Cooperative packed store: RPB*3/4 float4s per block, fully coalesced.
    const v4f* lds4  = (const v4f*)lds;
    const long obase = (long)blockIdx.x * (RPB * 3 / 4);
    if (full) {
        #pragma unroll
        for (int k = 0; k < 3; ++k) {
            const long oi = obase + tid + k * BLOCK;
            __builtin_nontemporal_store(lds4[tid + k * BLOCK], &out4[oi]);
        }
    } else {
        const long on4 = ((long)n * 3) / 4;
        #pragma unroll
        for (int k = 0; k < 3; ++k) {
            const long oi = obase + tid + k * BLOCK;
            if (oi < on4) {
                __builtin_nontemporal_store(lds4[tid + k * BLOCK], &out4[oi]);
            }
        }
    }
}

extern "C" void kernel_launch(void* const* d_in, const int* in_sizes, int n_in,
                              void* d_out, int out_size, void* d_ws, size_t ws_size,
                              hipStream_t stream) {
    const float* x     = (const float*)d_in[0];
    const float* W     = (const float*)d_in[1];
    const float* gamma = (const float*)d_in[2];
    const float* beta  = (const float*)d_in[3];
    v4f* out4 = (v4f*)d_out;

    int n = in_sizes[0] / 4;                 // number of rows (8,388,608)
    int grid = (n + RPB - 1) / RPB;          // 4096 blocks
    ln_linear_softmax_kernel<<<grid, BLOCK, 0, stream>>>(
        (const v4f*)x, W, gamma, beta, out4, n);
}